// Round 12
// baseline (211.108 us; speedup 1.0000x reference)
//
#include <hip/hip_runtime.h>

// ChannelAttentionBlock: per batch b, F = x[b] viewed as [4096,128] (row-major).
// S = F F^T ; P = softmax rows ; out[b] = F^T P -> [128, 4096].
//
// k0 cab_prep    : Fbb=bf16(x); FtFrag = fragment-major F^T; nrm; bmax.
// k0b cab_mx     : mxf[b] = max over batch-b block maxes
// k1 cab_rowstats: c2[n] = nsh_n - log2 sum_m 2^(S*L2E + nsh_n)  (C-S shift)
// k2 cab_out     : v12 BARRIER-FREE main loop: G1-A direct from L2-resident Fbb
//                  (16 rows x 64B contiguous per wave-instr), G2-A from FtFrag
//                  (16B/lane perfectly coalesced, round-11 proven), c2 via global
//                  float4; only LDS = wave-private W round-trip. 8 free-running
//                  wave streams/CU hide L2+exp+MFMA latency.
//
// S bytes/chain order identical in k1/k2 (bit-exact between passes).

typedef __attribute__((ext_vector_type(8))) __bf16 bf16x8;
typedef __attribute__((ext_vector_type(4))) float f32x4;
typedef __attribute__((ext_vector_type(4))) unsigned int u32x4;

#define MFMA16(a, b, c) __builtin_amdgcn_mfma_f32_16x16x32_bf16((a), (b), (c), 0, 0, 0)
#define GLOAD16(g, l)                                                       \
  __builtin_amdgcn_global_load_lds(                                         \
      (const __attribute__((address_space(1))) void*)(g),                   \
      (__attribute__((address_space(3))) void*)(l), 16, 0, 0)

static constexpr int NT = 4096;
static constexpr int DD = 128;
static constexpr float L2E = 1.4426950408889634f;

__device__ __forceinline__ unsigned short bfc(float f) {
  return __builtin_bit_cast(unsigned short, (__bf16)f);
}
__device__ __forceinline__ float bf2f(unsigned short u) {
  return (float)__builtin_bit_cast(__bf16, u);
}

// ---------------------------------------------------------------------------
// k0: fused cast + fragment-transpose + row norms. grid 512: b=blk&7, n0-block.
// FtFrag layout (per batch, 1 MB): chunk = (s*2 + nh)*8 + dt  (s = n-step),
//   chunk holds 64 lanes x 16B; lane l covers d = dt*16 + (l&15),
//   n = s*64 + nh*32 + (l>>4)*8 + j, j=0..7.
// ---------------------------------------------------------------------------
__global__ __launch_bounds__(256) void cab_prep(const float* __restrict__ x,
                                                ushort* __restrict__ Fbb,
                                                ushort* __restrict__ FtF,
                                                float* __restrict__ nrm,
                                                float* __restrict__ bmax) {
  const int blk = blockIdx.x;
  const int b = blk & 7, n0 = (blk >> 3) * 64;
  const float* F = x + ((size_t)b * NT + n0) * DD;
  ushort* Fo = Fbb + ((size_t)b * NT + n0) * DD;
  ushort* To = FtF + (size_t)b * DD * NT;

  __shared__ ushort T[128 * 68];  // [d][n-local], stride 136 B (8B-aligned rows)
  __shared__ float redw[4];

  const int t = threadIdx.x, seg = t & 15, rl = t >> 4;
  float lmax = 0.f;

#pragma unroll
  for (int i = 0; i < 4; ++i) {
    const int r = i * 16 + rl;
    float4 u = *(const float4*)(F + (size_t)r * DD + seg * 8);
    float4 v = *(const float4*)(F + (size_t)r * DD + seg * 8 + 4);
    ushort w[8] = {bfc(u.x), bfc(u.y), bfc(u.z), bfc(u.w),
                   bfc(v.x), bfc(v.y), bfc(v.z), bfc(v.w)};
    *(ushort4*)(Fo + (size_t)r * DD + seg * 8) = make_ushort4(w[0], w[1], w[2], w[3]);
    *(ushort4*)(Fo + (size_t)r * DD + seg * 8 + 4) = make_ushort4(w[4], w[5], w[6], w[7]);
    float s = 0.f;
#pragma unroll
    for (int j = 0; j < 8; ++j) {
      T[(seg * 8 + j) * 68 + r] = w[j];
      float f = bf2f(w[j]);
      s = fmaf(f, f, s);
    }
#pragma unroll
    for (int off = 1; off < 16; off <<= 1) s += __shfl_xor(s, off, 64);
    float rn = sqrtf(s);
    if (seg == 0) nrm[(size_t)b * NT + n0 + r] = rn;
    lmax = fmaxf(lmax, rn);
  }
#pragma unroll
  for (int off = 1; off < 64; off <<= 1) lmax = fmaxf(lmax, __shfl_xor(lmax, off, 64));
  if ((t & 63) == 0) redw[t >> 6] = lmax;
  __syncthreads();
  if (t == 0) bmax[blk] = fmaxf(fmaxf(redw[0], redw[1]), fmaxf(redw[2], redw[3]));

  // fragment-transpose out: idx -> (nh = idx>>9, dt = (idx>>6)&7, ln = idx&63)
#pragma unroll
  for (int i = 0; i < 4; ++i) {
    int idx = i * 256 + t;
    int nh = idx >> 9, dt = (idx >> 6) & 7, ln = idx & 63;
    int d = dt * 16 + (ln & 15), nl = nh * 32 + (ln >> 4) * 8;
    const ushort* p = &T[d * 68 + nl];
    uint2 q0 = *(const uint2*)p;
    uint2 q1 = *(const uint2*)(p + 4);
    u32x4 q = {q0.x, q0.y, q1.x, q1.y};
    *(u32x4*)(To + (size_t)(((n0 >> 6) * 2 + nh) * 8 + dt) * 512 + ln * 8) = q;
  }
}

// ---------------------------------------------------------------------------
// k0b: per-batch max of block maxes. grid 8 x 64.
// ---------------------------------------------------------------------------
__global__ __launch_bounds__(64) void cab_mx(const float* __restrict__ bmax,
                                             float* __restrict__ mxf) {
  const int b = blockIdx.x, l = threadIdx.x;
  float m = bmax[l * 8 + b];
#pragma unroll
  for (int off = 1; off < 64; off <<= 1) m = fmaxf(m, __shfl_xor(m, off, 64));
  if (l == 0) mxf[b] = m;
}

// ---------------------------------------------------------------------------
// k1: c2 stats. grid 512: b=blk&7, nb=(blk>>3)*64. Full-m pass, 1 barrier/step.
// (round-7 verbatim — measured good)
// ---------------------------------------------------------------------------
__global__ __launch_bounds__(256, 4) void cab_rowstats(const ushort* __restrict__ Fbb,
                                                       const float* __restrict__ nrm,
                                                       const float* __restrict__ mxf,
                                                       float* __restrict__ c2g) {
  const int b = blockIdx.x & 7;
  const int nb = (blockIdx.x >> 3) * 64;
  const ushort* Fb = Fbb + (size_t)b * NT * DD;

  const int t = threadIdx.x, lane = t & 63, wv = t >> 6;
  const int lcol = lane & 15, hi = lane >> 4;
  const int nh = wv >> 1, mq = wv & 1;

  __shared__ __align__(16) char FmB[2][16384];  // [64 m][16 chunks], swz ^(m&15)
  __shared__ float zred[64];

  int fmoff[4];
#pragma unroll
  for (int i = 0; i < 4; ++i) {
    int L = i * 256 + t;
    int m = L >> 4, c = (L & 15) ^ (m & 15);
    fmoff[i] = m * DD + c * 8;
  }

  bf16x8 afr[2][4];
#pragma unroll
  for (int nt = 0; nt < 2; ++nt)
#pragma unroll
    for (int ks = 0; ks < 4; ++ks)
      afr[nt][ks] = *(const bf16x8*)(Fb + (size_t)(nb + nh * 32 + nt * 16 + lcol) * DD +
                                     ks * 32 + hi * 8);

  const float mxv = mxf[b] * L2E;
  float nsh[8];
#pragma unroll
  for (int nt = 0; nt < 2; ++nt)
#pragma unroll
    for (int r = 0; r < 4; ++r)
      nsh[nt * 4 + r] = -nrm[(size_t)b * NT + nb + nh * 32 + nt * 16 + hi * 4 + r] * mxv;

#pragma unroll
  for (int i = 0; i < 4; ++i) GLOAD16(Fb + fmoff[i], &FmB[0][i * 4096 + wv * 1024]);
  __syncthreads();

  float zloc[8];
#pragma unroll
  for (int i = 0; i < 8; ++i) zloc[i] = 0.f;

  for (int s = 0; s < 64; ++s) {
    const int cur = s & 1;
    if (s < 63) {
      const ushort* src = Fb + (size_t)(s + 1) * 64 * DD;
#pragma unroll
      for (int i = 0; i < 4; ++i)
        GLOAD16(src + fmoff[i], &FmB[cur ^ 1][i * 4096 + wv * 1024]);
    }

    f32x4 sacc[2][2];
#pragma unroll
    for (int nt = 0; nt < 2; ++nt)
#pragma unroll
      for (int ms = 0; ms < 2; ++ms) sacc[nt][ms] = (f32x4){0.f, 0.f, 0.f, 0.f};
#pragma unroll
    for (int ms = 0; ms < 2; ++ms)
#pragma unroll
      for (int ks = 0; ks < 4; ++ks) {
        int ml = mq * 32 + ms * 16 + lcol;
        bf16x8 bb = *(const bf16x8*)&FmB[cur][ml * 256 + (((ks * 4 + hi) ^ lcol) << 4)];
#pragma unroll
        for (int nt = 0; nt < 2; ++nt) sacc[nt][ms] = MFMA16(afr[nt][ks], bb, sacc[nt][ms]);
      }
#pragma unroll
    for (int nt = 0; nt < 2; ++nt)
#pragma unroll
      for (int r = 0; r < 4; ++r)
        zloc[nt * 4 + r] += __builtin_amdgcn_exp2f(fmaf(sacc[nt][0][r], L2E, nsh[nt * 4 + r])) +
                            __builtin_amdgcn_exp2f(fmaf(sacc[nt][1][r], L2E, nsh[nt * 4 + r]));
    __syncthreads();
  }

#pragma unroll
  for (int i = 0; i < 8; ++i) {
#pragma unroll
    for (int off = 1; off < 16; off <<= 1) zloc[i] += __shfl_xor(zloc[i], off, 64);
  }
  if (mq == 1 && lcol == 0) {
#pragma unroll
    for (int i = 0; i < 8; ++i) zred[nh * 32 + (i >> 2) * 16 + hi * 4 + (i & 3)] = zloc[i];
  }
  __syncthreads();
  if (mq == 0 && lcol == 0) {
#pragma unroll
    for (int i = 0; i < 8; ++i) {
      int nloc = nh * 32 + (i >> 2) * 16 + hi * 4 + (i & 3);
      c2g[(size_t)b * NT + nb + nloc] = nsh[i] - __log2f(zloc[i] + zred[nloc]);
    }
  }
}

// ---------------------------------------------------------------------------
// k2: O = F^T W. grid 512: b=blk&7, mb0=(blk>>3)*64.  v12: BARRIER-FREE loop.
// Wave (mh=wv&1, nh=wv>>1): 32 m x 32 n per step; fmf in regs;
// G1-A direct from Fbb (16 rows x 64B/instr), G2-A from FtFrag (coalesced),
// c2 via global float4; LDS = wave-private W round-trip only (same-wave dep).
// ---------------------------------------------------------------------------
__global__ __launch_bounds__(256, 2) void cab_out(const ushort* __restrict__ Fbb,
                                                  const ushort* __restrict__ FtF,
                                                  const float* __restrict__ c2g,
                                                  float* __restrict__ out) {
  const int b = blockIdx.x & 7, mb0 = (blockIdx.x >> 3) * 64;
  const ushort* Fb = Fbb + (size_t)b * NT * DD;
  const ushort* Fr = FtF + (size_t)b * DD * NT;
  const float* c2p = c2g + (size_t)b * NT;

  const int t = threadIdx.x, lane = t & 63, wv = t >> 6;
  const int lcol = lane & 15, hi = lane >> 4;
  const int mh = wv & 1, nh = wv >> 1;

  // LDS: wave-private Wt (9216 B used) in loop; 32 KB epilogue scratch overlay.
  __shared__ __align__(16) char LB[32768];
  char* Wt = LB;

  // G1 B-operand: wave's 32 m-rows in registers
  bf16x8 fmf[2][4];
#pragma unroll
  for (int ms = 0; ms < 2; ++ms)
#pragma unroll
    for (int ks = 0; ks < 4; ++ks)
      fmf[ms][ks] = *(const bf16x8*)(Fb + (size_t)(mb0 + mh * 32 + ms * 16 + lcol) * DD +
                                     ks * 32 + hi * 8);

  f32x4 accO[8][2];  // [dt][msub]
#pragma unroll
  for (int dt = 0; dt < 8; ++dt)
#pragma unroll
    for (int ms = 0; ms < 2; ++ms) accO[dt][ms] = (f32x4){0.f, 0.f, 0.f, 0.f};

  const unsigned wtbase = wv * 2304;
  const ushort* a2w = Fr + (size_t)(nh * 8) * 512 + lane * 8;  // + s*8192 + dt*512
  const ushort* a1w = Fb + (size_t)(nh * 32 + lcol) * DD + hi * 8;  // + s*64*DD + nt*16*DD + ks*32
  const float* cw = c2p + nh * 32 + hi * 4;  // + s*64 + nt*16

  for (int s = 0; s < 64; ++s) {
    // G2-A from FtFrag (perfectly coalesced 16B/lane)
    const ushort* ap = a2w + (size_t)s * 8192;
    bf16x8 a2[8];
#pragma unroll
    for (int dt = 0; dt < 8; ++dt) a2[dt] = *(const bf16x8*)(ap + dt * 512);

    // G1-A direct from Fbb: wave = 16 rows x 64B contiguous per instr
    const ushort* rp = a1w + (size_t)s * 64 * DD;
    bf16x8 a1[2][4];
#pragma unroll
    for (int nt = 0; nt < 2; ++nt)
#pragma unroll
      for (int ks = 0; ks < 4; ++ks)
        a1[nt][ks] = *(const bf16x8*)(rp + nt * 16 * DD + ks * 32);

    // c2 per-lane (broadcast within 16-lane groups)
    float4 cv[2];
    cv[0] = *(const float4*)(cw + s * 64);
    cv[1] = *(const float4*)(cw + s * 64 + 16);

    // G1: S[wave's 32 n][wave's 32 m]; ks-chain identical to k1 -> same S
    f32x4 sacc[2][2];  // [nt][msub]
#pragma unroll
    for (int nt = 0; nt < 2; ++nt)
#pragma unroll
      for (int ms = 0; ms < 2; ++ms) sacc[nt][ms] = (f32x4){0.f, 0.f, 0.f, 0.f};
#pragma unroll
    for (int nt = 0; nt < 2; ++nt)
#pragma unroll
      for (int ks = 0; ks < 4; ++ks)
#pragma unroll
        for (int ms = 0; ms < 2; ++ms)
          sacc[nt][ms] = MFMA16(a1[nt][ks], fmf[ms][ks], sacc[nt][ms]);

    // W = 2^(S*L2E + c2) -> wave-private Wt [32 m][72 B rows]
#pragma unroll
    for (int nt = 0; nt < 2; ++nt) {
#pragma unroll
      for (int ms = 0; ms < 2; ++ms) {
        ushort4 wp;
        wp.x = bfc(__builtin_amdgcn_exp2f(fmaf(sacc[nt][ms][0], L2E, cv[nt].x)));
        wp.y = bfc(__builtin_amdgcn_exp2f(fmaf(sacc[nt][ms][1], L2E, cv[nt].y)));
        wp.z = bfc(__builtin_amdgcn_exp2f(fmaf(sacc[nt][ms][2], L2E, cv[nt].z)));
        wp.w = bfc(__builtin_amdgcn_exp2f(fmaf(sacc[nt][ms][3], L2E, cv[nt].w)));
        *(ushort4*)&Wt[wtbase + (ms * 16 + lcol) * 72 + nt * 32 + hi * 8] = wp;
      }
    }

    // G2: accO[dt][ms] += A2 x Wt(B)  (same-wave LDS dep only; no barrier)
    bf16x8 b2[2];
#pragma unroll
    for (int ms = 0; ms < 2; ++ms) {
      const char* p = &Wt[wtbase + (ms * 16 + lcol) * 72 + hi * 16];
      uint2 lo = *(const uint2*)p;
      uint2 h2 = *(const uint2*)(p + 8);
      b2[ms] = __builtin_bit_cast(bf16x8, (u32x4){lo.x, lo.y, h2.x, h2.y});
    }
#pragma unroll
    for (int dt = 0; dt < 8; ++dt)
#pragma unroll
      for (int ms = 0; ms < 2; ++ms) accO[dt][ms] = MFMA16(a2[dt], b2[ms], accO[dt][ms]);
  }

  // epilogue: sum nh-partials via LDS overlay (barriers only here)
  __syncthreads();  // all waves done with Wt
  float* red = (float*)LB;
  if (nh == 1) {
#pragma unroll
    for (int dt = 0; dt < 8; ++dt)
#pragma unroll
      for (int ms = 0; ms < 2; ++ms)
#pragma unroll
        for (int r = 0; r < 4; ++r)
          red[mh * 4096 + (dt * 8 + ms * 4 + r) * 64 + lane] = accO[dt][ms][r];
  }
  __syncthreads();
  if (nh == 0) {
    float* Ob = out + (size_t)b * DD * NT;
#pragma unroll
    for (int dt = 0; dt < 8; ++dt)
#pragma unroll
      for (int ms = 0; ms < 2; ++ms)
#pragma unroll
        for (int r = 0; r < 4; ++r) {
          float v = accO[dt][ms][r] + red[mh * 4096 + (dt * 8 + ms * 4 + r) * 64 + lane];
          Ob[(size_t)(dt * 16 + hi * 4 + r) * NT + mb0 + mh * 32 + ms * 16 + lcol] = v;
        }
  }
}

extern "C" void kernel_launch(void* const* d_in, const int* in_sizes, int n_in,
                              void* d_out, int out_size, void* d_ws, size_t ws_size,
                              hipStream_t stream) {
  const float* x = (const float*)d_in[0];
  float* out = (float*)d_out;
  char* ws = (char*)d_ws;
  ushort* Fbb = (ushort*)ws;                         // 8 MB
  ushort* FtF = (ushort*)(ws + (8u << 20));          // 8 MB (fragment-major F^T)
  float* nrm = (float*)(ws + (16u << 20));           // 128 KB
  float* bmax = (float*)(ws + (16u << 20) + 131072); // 2 KB
  float* mxf = (float*)(ws + (16u << 20) + 133120);  // 32 B (pad to 1 KB)
  float* c2 = (float*)(ws + (16u << 20) + 134144);   // 128 KB

  hipLaunchKernelGGL(cab_prep, dim3(512), dim3(256), 0, stream, x, Fbb, FtF, nrm, bmax);
  hipLaunchKernelGGL(cab_mx, dim3(8), dim3(64), 0, stream, bmax, mxf);
  hipLaunchKernelGGL(cab_rowstats, dim3(512), dim3(256), 0, stream, Fbb, nrm, mxf, c2);
  hipLaunchKernelGGL(cab_out, dim3(512), dim3(256), 0, stream, Fbb, FtF, c2, out);
}

// Round 13
// 151.444 us; speedup vs baseline: 1.3940x; 1.3940x over previous
//
#include <hip/hip_runtime.h>

// ChannelAttentionBlock: per batch b, F = x[b] viewed as [4096,128] (row-major).
// S = F F^T ; P = softmax rows ; out[b] = F^T P -> [128, 4096].
//
// k0 cab_prep    : Fbb=bf16(x); FtFrag = fragment-major F^T; nrm; bmax.
// k0b cab_mx     : mxf[b] = max over batch-b block maxes
// k1 cab_rowstats: c2[n] = nsh_n - log2 sum_m 2^(S*L2E + nsh_n)  (C-S shift)
// k2 cab_out     : v13 wave-autonomous: each wave DMAs its PRIVATE double-buffered
//                  A-tile (no cross-wave LDS sharing -> ZERO barriers in loop);
//                  per-wave counted vmcnt(18) keeps 1-step DMA prefetch alive
//                  (issue order pinned: [a2/c2 10] -> [DMA 8] -> vmcnt(18) -> G1;
//                  a2 BEFORE DMA so the compiler's a2-wait doesn't drain prefetch).
//                  G2-A from FtFrag (coalesced, round-11 proven). W wave-private.
//
// S bytes/chain order identical in k1/k2 (bit-exact between passes).

typedef __attribute__((ext_vector_type(8))) __bf16 bf16x8;
typedef __attribute__((ext_vector_type(4))) float f32x4;
typedef __attribute__((ext_vector_type(4))) unsigned int u32x4;

#define MFMA16(a, b, c) __builtin_amdgcn_mfma_f32_16x16x32_bf16((a), (b), (c), 0, 0, 0)
#define GLOAD16(g, l)                                                       \
  __builtin_amdgcn_global_load_lds(                                         \
      (const __attribute__((address_space(1))) void*)(g),                   \
      (__attribute__((address_space(3))) void*)(l), 16, 0, 0)

static constexpr int NT = 4096;
static constexpr int DD = 128;
static constexpr float L2E = 1.4426950408889634f;

__device__ __forceinline__ unsigned short bfc(float f) {
  return __builtin_bit_cast(unsigned short, (__bf16)f);
}
__device__ __forceinline__ float bf2f(unsigned short u) {
  return (float)__builtin_bit_cast(__bf16, u);
}

// ---------------------------------------------------------------------------
// k0: fused cast + fragment-transpose + row norms. grid 512: b=blk&7, n0-block.
// FtFrag layout (per batch, 1 MB): chunk = (s*2 + nh)*8 + dt  (s = n-step),
//   chunk holds 64 lanes x 16B; lane l covers d = dt*16 + (l&15),
//   n = s*64 + nh*32 + (l>>4)*8 + j, j=0..7.
// ---------------------------------------------------------------------------
__global__ __launch_bounds__(256) void cab_prep(const float* __restrict__ x,
                                                ushort* __restrict__ Fbb,
                                                ushort* __restrict__ FtF,
                                                float* __restrict__ nrm,
                                                float* __restrict__ bmax) {
  const int blk = blockIdx.x;
  const int b = blk & 7, n0 = (blk >> 3) * 64;
  const float* F = x + ((size_t)b * NT + n0) * DD;
  ushort* Fo = Fbb + ((size_t)b * NT + n0) * DD;
  ushort* To = FtF + (size_t)b * DD * NT;

  __shared__ ushort T[128 * 68];  // [d][n-local], stride 136 B (8B-aligned rows)
  __shared__ float redw[4];

  const int t = threadIdx.x, seg = t & 15, rl = t >> 4;
  float lmax = 0.f;

#pragma unroll
  for (int i = 0; i < 4; ++i) {
    const int r = i * 16 + rl;
    float4 u = *(const float4*)(F + (size_t)r * DD + seg * 8);
    float4 v = *(const float4*)(F + (size_t)r * DD + seg * 8 + 4);
    ushort w[8] = {bfc(u.x), bfc(u.y), bfc(u.z), bfc(u.w),
                   bfc(v.x), bfc(v.y), bfc(v.z), bfc(v.w)};
    *(ushort4*)(Fo + (size_t)r * DD + seg * 8) = make_ushort4(w[0], w[1], w[2], w[3]);
    *(ushort4*)(Fo + (size_t)r * DD + seg * 8 + 4) = make_ushort4(w[4], w[5], w[6], w[7]);
    float s = 0.f;
#pragma unroll
    for (int j = 0; j < 8; ++j) {
      T[(seg * 8 + j) * 68 + r] = w[j];
      float f = bf2f(w[j]);
      s = fmaf(f, f, s);
    }
#pragma unroll
    for (int off = 1; off < 16; off <<= 1) s += __shfl_xor(s, off, 64);
    float rn = sqrtf(s);
    if (seg == 0) nrm[(size_t)b * NT + n0 + r] = rn;
    lmax = fmaxf(lmax, rn);
  }
#pragma unroll
  for (int off = 1; off < 64; off <<= 1) lmax = fmaxf(lmax, __shfl_xor(lmax, off, 64));
  if ((t & 63) == 0) redw[t >> 6] = lmax;
  __syncthreads();
  if (t == 0) bmax[blk] = fmaxf(fmaxf(redw[0], redw[1]), fmaxf(redw[2], redw[3]));

  // fragment-transpose out: idx -> (nh = idx>>9, dt = (idx>>6)&7, ln = idx&63)
#pragma unroll
  for (int i = 0; i < 4; ++i) {
    int idx = i * 256 + t;
    int nh = idx >> 9, dt = (idx >> 6) & 7, ln = idx & 63;
    int d = dt * 16 + (ln & 15), nl = nh * 32 + (ln >> 4) * 8;
    const ushort* p = &T[d * 68 + nl];
    uint2 q0 = *(const uint2*)p;
    uint2 q1 = *(const uint2*)(p + 4);
    u32x4 q = {q0.x, q0.y, q1.x, q1.y};
    *(u32x4*)(To + (size_t)(((n0 >> 6) * 2 + nh) * 8 + dt) * 512 + ln * 8) = q;
  }
}

// ---------------------------------------------------------------------------
// k0b: per-batch max of block maxes. grid 8 x 64.
// ---------------------------------------------------------------------------
__global__ __launch_bounds__(64) void cab_mx(const float* __restrict__ bmax,
                                             float* __restrict__ mxf) {
  const int b = blockIdx.x, l = threadIdx.x;
  float m = bmax[l * 8 + b];
#pragma unroll
  for (int off = 1; off < 64; off <<= 1) m = fmaxf(m, __shfl_xor(m, off, 64));
  if (l == 0) mxf[b] = m;
}

// ---------------------------------------------------------------------------
// k1: c2 stats. grid 512: b=blk&7, nb=(blk>>3)*64. Full-m pass, 1 barrier/step.
// (round-7 verbatim — measured good)
// ---------------------------------------------------------------------------
__global__ __launch_bounds__(256, 4) void cab_rowstats(const ushort* __restrict__ Fbb,
                                                       const float* __restrict__ nrm,
                                                       const float* __restrict__ mxf,
                                                       float* __restrict__ c2g) {
  const int b = blockIdx.x & 7;
  const int nb = (blockIdx.x >> 3) * 64;
  const ushort* Fb = Fbb + (size_t)b * NT * DD;

  const int t = threadIdx.x, lane = t & 63, wv = t >> 6;
  const int lcol = lane & 15, hi = lane >> 4;
  const int nh = wv >> 1, mq = wv & 1;

  __shared__ __align__(16) char FmB[2][16384];  // [64 m][16 chunks], swz ^(m&15)
  __shared__ float zred[64];

  int fmoff[4];
#pragma unroll
  for (int i = 0; i < 4; ++i) {
    int L = i * 256 + t;
    int m = L >> 4, c = (L & 15) ^ (m & 15);
    fmoff[i] = m * DD + c * 8;
  }

  bf16x8 afr[2][4];
#pragma unroll
  for (int nt = 0; nt < 2; ++nt)
#pragma unroll
    for (int ks = 0; ks < 4; ++ks)
      afr[nt][ks] = *(const bf16x8*)(Fb + (size_t)(nb + nh * 32 + nt * 16 + lcol) * DD +
                                     ks * 32 + hi * 8);

  const float mxv = mxf[b] * L2E;
  float nsh[8];
#pragma unroll
  for (int nt = 0; nt < 2; ++nt)
#pragma unroll
    for (int r = 0; r < 4; ++r)
      nsh[nt * 4 + r] = -nrm[(size_t)b * NT + nb + nh * 32 + nt * 16 + hi * 4 + r] * mxv;

#pragma unroll
  for (int i = 0; i < 4; ++i) GLOAD16(Fb + fmoff[i], &FmB[0][i * 4096 + wv * 1024]);
  __syncthreads();

  float zloc[8];
#pragma unroll
  for (int i = 0; i < 8; ++i) zloc[i] = 0.f;

  for (int s = 0; s < 64; ++s) {
    const int cur = s & 1;
    if (s < 63) {
      const ushort* src = Fb + (size_t)(s + 1) * 64 * DD;
#pragma unroll
      for (int i = 0; i < 4; ++i)
        GLOAD16(src + fmoff[i], &FmB[cur ^ 1][i * 4096 + wv * 1024]);
    }

    f32x4 sacc[2][2];
#pragma unroll
    for (int nt = 0; nt < 2; ++nt)
#pragma unroll
      for (int ms = 0; ms < 2; ++ms) sacc[nt][ms] = (f32x4){0.f, 0.f, 0.f, 0.f};
#pragma unroll
    for (int ms = 0; ms < 2; ++ms)
#pragma unroll
      for (int ks = 0; ks < 4; ++ks) {
        int ml = mq * 32 + ms * 16 + lcol;
        bf16x8 bb = *(const bf16x8*)&FmB[cur][ml * 256 + (((ks * 4 + hi) ^ lcol) << 4)];
#pragma unroll
        for (int nt = 0; nt < 2; ++nt) sacc[nt][ms] = MFMA16(afr[nt][ks], bb, sacc[nt][ms]);
      }
#pragma unroll
    for (int nt = 0; nt < 2; ++nt)
#pragma unroll
      for (int r = 0; r < 4; ++r)
        zloc[nt * 4 + r] += __builtin_amdgcn_exp2f(fmaf(sacc[nt][0][r], L2E, nsh[nt * 4 + r])) +
                            __builtin_amdgcn_exp2f(fmaf(sacc[nt][1][r], L2E, nsh[nt * 4 + r]));
    __syncthreads();
  }

#pragma unroll
  for (int i = 0; i < 8; ++i) {
#pragma unroll
    for (int off = 1; off < 16; off <<= 1) zloc[i] += __shfl_xor(zloc[i], off, 64);
  }
  if (mq == 1 && lcol == 0) {
#pragma unroll
    for (int i = 0; i < 8; ++i) zred[nh * 32 + (i >> 2) * 16 + hi * 4 + (i & 3)] = zloc[i];
  }
  __syncthreads();
  if (mq == 0 && lcol == 0) {
#pragma unroll
    for (int i = 0; i < 8; ++i) {
      int nloc = nh * 32 + (i >> 2) * 16 + hi * 4 + (i & 3);
      c2g[(size_t)b * NT + nb + nloc] = nsh[i] - __log2f(zloc[i] + zred[nloc]);
    }
  }
}

// ---------------------------------------------------------------------------
// k2: O = F^T W. grid 512: b=blk&7, mb0=(blk>>3)*64.  v13: wave-autonomous.
// Wave (mh=wv&1, nh=wv>>1): 32 m x 32 n per step; fmf in regs; W wave-private.
// Per-wave PRIVATE double-buffered A-tile (8KB x2) via global_load_lds;
// no barriers in main loop; counted vmcnt keeps prefetch in flight.
// ---------------------------------------------------------------------------
__global__ __launch_bounds__(256, 2) void cab_out(const ushort* __restrict__ Fbb,
                                                  const ushort* __restrict__ FtF,
                                                  const float* __restrict__ c2g,
                                                  float* __restrict__ out) {
  const int b = blockIdx.x & 7, mb0 = (blockIdx.x >> 3) * 64;
  const ushort* Fb = Fbb + (size_t)b * NT * DD;
  const ushort* Fr = FtF + (size_t)b * DD * NT;
  const float* c2p = c2g + (size_t)b * NT;

  const int t = threadIdx.x, lane = t & 63, wv = t >> 6;
  const int lcol = lane & 15, hi = lane >> 4;
  const int mh = wv & 1, nh = wv >> 1;

  // LDS: 4 x (16 KB private dbuf A-tile) + 4 x 2304 Wt = 74752 B
  __shared__ __align__(16) char LB[74752];
  char* AW = LB + wv * 16384;          // this wave's [2][32 rows][256 B], swz ^(r&15)
  char* Wt = LB + 65536 + wv * 2304;   // wave-private W

  // per-wave DMA source offsets (element units): instr i stages rows i*4..i*4+3
  int dmoff[8];
#pragma unroll
  for (int i = 0; i < 8; ++i) {
    int r = i * 4 + hi;  // row_local 0..31
    dmoff[i] = (nh * 32 + r) * DD + ((lcol ^ (r & 15)) * 8);
  }

  // G1 B-operand: wave's 32 m-rows in registers
  bf16x8 fmf[2][4];
#pragma unroll
  for (int ms = 0; ms < 2; ++ms)
#pragma unroll
    for (int ks = 0; ks < 4; ++ks)
      fmf[ms][ks] = *(const bf16x8*)(Fb + (size_t)(mb0 + mh * 32 + ms * 16 + lcol) * DD +
                                     ks * 32 + hi * 8);

  f32x4 accO[8][2];  // [dt][msub]
#pragma unroll
  for (int dt = 0; dt < 8; ++dt)
#pragma unroll
    for (int ms = 0; ms < 2; ++ms) accO[dt][ms] = (f32x4){0.f, 0.f, 0.f, 0.f};

  const ushort* a2w = Fr + (size_t)(nh * 8) * 512 + lane * 8;      // + s*8192 + dt*512
  const float* cw = c2p + nh * 32 + hi * 4;                        // + s*64 + nt*16

  // prologue: stage step 0 into private buf 0
#pragma unroll
  for (int i = 0; i < 8; ++i) GLOAD16(Fb + dmoff[i], AW + i * 1024);

  for (int s = 0; s < 64; ++s) {
    const int cur = s & 1;

    __builtin_amdgcn_sched_barrier(0);
    // group 1: a2 + c2 loads (10 vmem) -- BEFORE DMA so their wait spares prefetch
    bf16x8 a2[8];
    const ushort* ap = a2w + (size_t)s * 8192;
#pragma unroll
    for (int dt = 0; dt < 8; ++dt) a2[dt] = *(const bf16x8*)(ap + dt * 512);
    float4 cv[2];
    cv[0] = *(const float4*)(cw + s * 64);
    cv[1] = *(const float4*)(cw + s * 64 + 16);
    __builtin_amdgcn_sched_barrier(0);

    // group 2: DMA(s+1) into the other private buffer (8 vmem)
    if (s < 63) {
      const ushort* fs = Fb + (size_t)(s + 1) * 64 * DD;
      char* dst = AW + (cur ^ 1) * 8192;
#pragma unroll
      for (int i = 0; i < 8; ++i) GLOAD16(fs + dmoff[i], dst + i * 1024);
    }
    __builtin_amdgcn_sched_barrier(0);

    // retire DMA(s) (oldest 8), keep a2(s)[10] + DMA(s+1)[8] in flight
    if (s < 63) {
      asm volatile("s_waitcnt vmcnt(18)" ::: "memory");
    } else {
      asm volatile("s_waitcnt vmcnt(10)" ::: "memory");
    }
    __builtin_amdgcn_sched_barrier(0);

    // G1: S[wave's 32 n][wave's 32 m] from private LDS; ks-chain == k1 -> same S
    f32x4 sacc[2][2];  // [nt][msub]
#pragma unroll
    for (int nt = 0; nt < 2; ++nt)
#pragma unroll
      for (int ms = 0; ms < 2; ++ms) sacc[nt][ms] = (f32x4){0.f, 0.f, 0.f, 0.f};
#pragma unroll
    for (int nt = 0; nt < 2; ++nt)
#pragma unroll
      for (int ks = 0; ks < 4; ++ks) {
        bf16x8 a = *(const bf16x8*)&AW[cur * 8192 + (nt * 16 + lcol) * 256 +
                                       (((ks * 4 + hi) ^ lcol) << 4)];
#pragma unroll
        for (int ms = 0; ms < 2; ++ms) sacc[nt][ms] = MFMA16(a, fmf[ms][ks], sacc[nt][ms]);
      }

    // W = 2^(S*L2E + c2) -> wave-private Wt [32 m][72 B rows]
#pragma unroll
    for (int nt = 0; nt < 2; ++nt) {
#pragma unroll
      for (int ms = 0; ms < 2; ++ms) {
        ushort4 wp;
        wp.x = bfc(__builtin_amdgcn_exp2f(fmaf(sacc[nt][ms][0], L2E, cv[nt].x)));
        wp.y = bfc(__builtin_amdgcn_exp2f(fmaf(sacc[nt][ms][1], L2E, cv[nt].y)));
        wp.z = bfc(__builtin_amdgcn_exp2f(fmaf(sacc[nt][ms][2], L2E, cv[nt].z)));
        wp.w = bfc(__builtin_amdgcn_exp2f(fmaf(sacc[nt][ms][3], L2E, cv[nt].w)));
        *(ushort4*)&Wt[(ms * 16 + lcol) * 72 + nt * 32 + hi * 8] = wp;
      }
    }

    // G2: accO[dt][ms] += A2(FtFrag regs) x Wt(B)  (same-wave LDS dep only)
    bf16x8 b2[2];
#pragma unroll
    for (int ms = 0; ms < 2; ++ms) {
      const char* p = &Wt[(ms * 16 + lcol) * 72 + hi * 16];
      uint2 lo = *(const uint2*)p;
      uint2 h2 = *(const uint2*)(p + 8);
      b2[ms] = __builtin_bit_cast(bf16x8, (u32x4){lo.x, lo.y, h2.x, h2.y});
    }
#pragma unroll
    for (int dt = 0; dt < 8; ++dt)
#pragma unroll
      for (int ms = 0; ms < 2; ++ms) accO[dt][ms] = MFMA16(a2[dt], b2[ms], accO[dt][ms]);
  }

  // epilogue: sum nh-partials via LDS overlay (barriers only here)
  __syncthreads();
  float* red = (float*)LB;
  if (nh == 1) {
#pragma unroll
    for (int dt = 0; dt < 8; ++dt)
#pragma unroll
      for (int ms = 0; ms < 2; ++ms)
#pragma unroll
        for (int r = 0; r < 4; ++r)
          red[mh * 4096 + (dt * 8 + ms * 4 + r) * 64 + lane] = accO[dt][ms][r];
  }
  __syncthreads();
  if (nh == 0) {
    float* Ob = out + (size_t)b * DD * NT;
#pragma unroll
    for (int dt = 0; dt < 8; ++dt)
#pragma unroll
      for (int ms = 0; ms < 2; ++ms)
#pragma unroll
        for (int r = 0; r < 4; ++r) {
          float v = accO[dt][ms][r] + red[mh * 4096 + (dt * 8 + ms * 4 + r) * 64 + lane];
          Ob[(size_t)(dt * 16 + hi * 4 + r) * NT + mb0 + mh * 32 + ms * 16 + lcol] = v;
        }
  }
}

extern "C" void kernel_launch(void* const* d_in, const int* in_sizes, int n_in,
                              void* d_out, int out_size, void* d_ws, size_t ws_size,
                              hipStream_t stream) {
  const float* x = (const float*)d_in[0];
  float* out = (float*)d_out;
  char* ws = (char*)d_ws;
  ushort* Fbb = (ushort*)ws;                         // 8 MB
  ushort* FtF = (ushort*)(ws + (8u << 20));          // 8 MB (fragment-major F^T)
  float* nrm = (float*)(ws + (16u << 20));           // 128 KB
  float* bmax = (float*)(ws + (16u << 20) + 131072); // 2 KB
  float* mxf = (float*)(ws + (16u << 20) + 133120);  // 32 B (pad to 1 KB)
  float* c2 = (float*)(ws + (16u << 20) + 134144);   // 128 KB

  hipLaunchKernelGGL(cab_prep, dim3(512), dim3(256), 0, stream, x, Fbb, FtF, nrm, bmax);
  hipLaunchKernelGGL(cab_mx, dim3(8), dim3(64), 0, stream, bmax, mxf);
  hipLaunchKernelGGL(cab_rowstats, dim3(512), dim3(256), 0, stream, Fbb, nrm, mxf, c2);
  hipLaunchKernelGGL(cab_out, dim3(512), dim3(256), 0, stream, Fbb, FtF, c2, out);
}

// Round 14
// 146.620 us; speedup vs baseline: 1.4398x; 1.0329x over previous
//
#include <hip/hip_runtime.h>

// ChannelAttentionBlock: per batch b, F = x[b] viewed as [4096,128] (row-major).
// S = F F^T ; P = softmax rows ; out[b] = F^T P -> [128, 4096].
//
// k0 cab_prep    : Fbb=bf16(x); FtFrag = fragment-major F^T; nrm; mxf via atomicMax.
// k1 cab_rowstats: c2[n] = nsh_n - log2 sum_m 2^(S*L2E + nsh_n)  (C-S shift)
// k2 cab_out     : round-11 structure (shared FnB staging + FtFrag G2-A +
//                  wave-private W) upgraded to v14: TRIPLE-buffered FnB, plain
//                  s_barrier (no vmcnt(0) drain). Issue order pinned
//                  [a2+cv] -> [DMA(s+2)]: the compiler's a2 vmcnt wait retires
//                  this wave's DMA(s+1) before the barrier -> cross-wave safe,
//                  2-step prefetch, no correlated drain stall (T3/T4 minimal).
//
// S bytes/chain order identical in k1/k2 (bit-exact between passes).

typedef __attribute__((ext_vector_type(8))) __bf16 bf16x8;
typedef __attribute__((ext_vector_type(4))) float f32x4;
typedef __attribute__((ext_vector_type(4))) unsigned int u32x4;

#define MFMA16(a, b, c) __builtin_amdgcn_mfma_f32_16x16x32_bf16((a), (b), (c), 0, 0, 0)
#define GLOAD16(g, l)                                                       \
  __builtin_amdgcn_global_load_lds(                                         \
      (const __attribute__((address_space(1))) void*)(g),                   \
      (__attribute__((address_space(3))) void*)(l), 16, 0, 0)
#define SBAR()                                                              \
  do {                                                                      \
    __builtin_amdgcn_sched_barrier(0);                                      \
    __builtin_amdgcn_s_barrier();                                           \
    __builtin_amdgcn_sched_barrier(0);                                      \
  } while (0)

static constexpr int NT = 4096;
static constexpr int DD = 128;
static constexpr float L2E = 1.4426950408889634f;

__device__ __forceinline__ unsigned short bfc(float f) {
  return __builtin_bit_cast(unsigned short, (__bf16)f);
}
__device__ __forceinline__ float bf2f(unsigned short u) {
  return (float)__builtin_bit_cast(__bf16, u);
}

// ---------------------------------------------------------------------------
// k0: fused cast + fragment-transpose + row norms + atomicMax batch-max.
// grid 512: b=blk&7, n0=(blk>>3)*64.
// FtFrag layout (per batch, 1 MB): chunk = (s*2 + nh)*8 + dt  (s = n-step),
//   chunk holds 64 lanes x 16B; lane l covers d = dt*16 + (l&15),
//   n = s*64 + nh*32 + (l>>4)*8 + j, j=0..7.
// ---------------------------------------------------------------------------
__global__ __launch_bounds__(256) void cab_prep(const float* __restrict__ x,
                                                ushort* __restrict__ Fbb,
                                                ushort* __restrict__ FtF,
                                                float* __restrict__ nrm,
                                                unsigned int* __restrict__ mxfU) {
  const int blk = blockIdx.x;
  const int b = blk & 7, n0 = (blk >> 3) * 64;
  const float* F = x + ((size_t)b * NT + n0) * DD;
  ushort* Fo = Fbb + ((size_t)b * NT + n0) * DD;
  ushort* To = FtF + (size_t)b * DD * NT;

  __shared__ ushort T[128 * 68];  // [d][n-local], stride 136 B (8B-aligned rows)
  __shared__ float redw[4];

  const int t = threadIdx.x, seg = t & 15, rl = t >> 4;
  float lmax = 0.f;

#pragma unroll
  for (int i = 0; i < 4; ++i) {
    const int r = i * 16 + rl;
    float4 u = *(const float4*)(F + (size_t)r * DD + seg * 8);
    float4 v = *(const float4*)(F + (size_t)r * DD + seg * 8 + 4);
    ushort w[8] = {bfc(u.x), bfc(u.y), bfc(u.z), bfc(u.w),
                   bfc(v.x), bfc(v.y), bfc(v.z), bfc(v.w)};
    *(ushort4*)(Fo + (size_t)r * DD + seg * 8) = make_ushort4(w[0], w[1], w[2], w[3]);
    *(ushort4*)(Fo + (size_t)r * DD + seg * 8 + 4) = make_ushort4(w[4], w[5], w[6], w[7]);
    float s = 0.f;
#pragma unroll
    for (int j = 0; j < 8; ++j) {
      T[(seg * 8 + j) * 68 + r] = w[j];
      float f = bf2f(w[j]);
      s = fmaf(f, f, s);
    }
#pragma unroll
    for (int off = 1; off < 16; off <<= 1) s += __shfl_xor(s, off, 64);
    float rn = sqrtf(s);
    if (seg == 0) nrm[(size_t)b * NT + n0 + r] = rn;
    lmax = fmaxf(lmax, rn);
  }
#pragma unroll
  for (int off = 1; off < 64; off <<= 1) lmax = fmaxf(lmax, __shfl_xor(lmax, off, 64));
  if ((t & 63) == 0) redw[t >> 6] = lmax;
  __syncthreads();
  if (t == 0) {
    float v = fmaxf(fmaxf(redw[0], redw[1]), fmaxf(redw[2], redw[3]));
    atomicMax(mxfU + b, __float_as_uint(v));  // norms >= 0: bits monotone
  }

  // fragment-transpose out: idx -> (nh = idx>>9, dt = (idx>>6)&7, ln = idx&63)
#pragma unroll
  for (int i = 0; i < 4; ++i) {
    int idx = i * 256 + t;
    int nh = idx >> 9, dt = (idx >> 6) & 7, ln = idx & 63;
    int d = dt * 16 + (ln & 15), nl = nh * 32 + (ln >> 4) * 8;
    const ushort* p = &T[d * 68 + nl];
    uint2 q0 = *(const uint2*)p;
    uint2 q1 = *(const uint2*)(p + 4);
    u32x4 q = {q0.x, q0.y, q1.x, q1.y};
    *(u32x4*)(To + (size_t)(((n0 >> 6) * 2 + nh) * 8 + dt) * 512 + ln * 8) = q;
  }
}

// ---------------------------------------------------------------------------
// k1: c2 stats. grid 512: b=blk&7, nb=(blk>>3)*64. Full-m pass, 1 barrier/step.
// (round-7/11 verbatim — measured good)
// ---------------------------------------------------------------------------
__global__ __launch_bounds__(256, 4) void cab_rowstats(const ushort* __restrict__ Fbb,
                                                       const float* __restrict__ nrm,
                                                       const float* __restrict__ mxf,
                                                       float* __restrict__ c2g) {
  const int b = blockIdx.x & 7;
  const int nb = (blockIdx.x >> 3) * 64;
  const ushort* Fb = Fbb + (size_t)b * NT * DD;

  const int t = threadIdx.x, lane = t & 63, wv = t >> 6;
  const int lcol = lane & 15, hi = lane >> 4;
  const int nh = wv >> 1, mq = wv & 1;

  __shared__ __align__(16) char FmB[2][16384];  // [64 m][16 chunks], swz ^(m&15)
  __shared__ float zred[64];

  int fmoff[4];
#pragma unroll
  for (int i = 0; i < 4; ++i) {
    int L = i * 256 + t;
    int m = L >> 4, c = (L & 15) ^ (m & 15);
    fmoff[i] = m * DD + c * 8;
  }

  bf16x8 afr[2][4];
#pragma unroll
  for (int nt = 0; nt < 2; ++nt)
#pragma unroll
    for (int ks = 0; ks < 4; ++ks)
      afr[nt][ks] = *(const bf16x8*)(Fb + (size_t)(nb + nh * 32 + nt * 16 + lcol) * DD +
                                     ks * 32 + hi * 8);

  const float mxv = mxf[b] * L2E;
  float nsh[8];
#pragma unroll
  for (int nt = 0; nt < 2; ++nt)
#pragma unroll
    for (int r = 0; r < 4; ++r)
      nsh[nt * 4 + r] = -nrm[(size_t)b * NT + nb + nh * 32 + nt * 16 + hi * 4 + r] * mxv;

#pragma unroll
  for (int i = 0; i < 4; ++i) GLOAD16(Fb + fmoff[i], &FmB[0][i * 4096 + wv * 1024]);
  __syncthreads();

  float zloc[8];
#pragma unroll
  for (int i = 0; i < 8; ++i) zloc[i] = 0.f;

  for (int s = 0; s < 64; ++s) {
    const int cur = s & 1;
    if (s < 63) {
      const ushort* src = Fb + (size_t)(s + 1) * 64 * DD;
#pragma unroll
      for (int i = 0; i < 4; ++i)
        GLOAD16(src + fmoff[i], &FmB[cur ^ 1][i * 4096 + wv * 1024]);
    }

    f32x4 sacc[2][2];
#pragma unroll
    for (int nt = 0; nt < 2; ++nt)
#pragma unroll
      for (int ms = 0; ms < 2; ++ms) sacc[nt][ms] = (f32x4){0.f, 0.f, 0.f, 0.f};
#pragma unroll
    for (int ms = 0; ms < 2; ++ms)
#pragma unroll
      for (int ks = 0; ks < 4; ++ks) {
        int ml = mq * 32 + ms * 16 + lcol;
        bf16x8 bb = *(const bf16x8*)&FmB[cur][ml * 256 + (((ks * 4 + hi) ^ lcol) << 4)];
#pragma unroll
        for (int nt = 0; nt < 2; ++nt) sacc[nt][ms] = MFMA16(afr[nt][ks], bb, sacc[nt][ms]);
      }
#pragma unroll
    for (int nt = 0; nt < 2; ++nt)
#pragma unroll
      for (int r = 0; r < 4; ++r)
        zloc[nt * 4 + r] += __builtin_amdgcn_exp2f(fmaf(sacc[nt][0][r], L2E, nsh[nt * 4 + r])) +
                            __builtin_amdgcn_exp2f(fmaf(sacc[nt][1][r], L2E, nsh[nt * 4 + r]));
    __syncthreads();
  }

#pragma unroll
  for (int i = 0; i < 8; ++i) {
#pragma unroll
    for (int off = 1; off < 16; off <<= 1) zloc[i] += __shfl_xor(zloc[i], off, 64);
  }
  if (mq == 1 && lcol == 0) {
#pragma unroll
    for (int i = 0; i < 8; ++i) zred[nh * 32 + (i >> 2) * 16 + hi * 4 + (i & 3)] = zloc[i];
  }
  __syncthreads();
  if (mq == 0 && lcol == 0) {
#pragma unroll
    for (int i = 0; i < 8; ++i) {
      int nloc = nh * 32 + (i >> 2) * 16 + hi * 4 + (i & 3);
      c2g[(size_t)b * NT + nb + nloc] = nsh[i] - __log2f(zloc[i] + zred[nloc]);
    }
  }
}

// ---------------------------------------------------------------------------
// k2: O = F^T W. grid 512: b=blk&7, mb0=(blk>>3)*64.  v14: triple-buffered FnB
// + plain s_barrier (no vmcnt(0) drain). Per step, pinned issue order:
//   [a2 (FtFrag) + cv loads] -> [DMA(s+2) -> buf (s+2)%3] -> G1 -> W -> G2 -> SBAR.
// Compiler's a2 vmcnt wait (before G2) retires this wave's DMA(s+1) -> barrier
// publishes it for step s+1's readers. Hazards: WAR on buf((s+2)%3) protected
// by the end-of-(s-1) barrier; RAW on buf(s) by the a2(s-1) wait in step s-1.
// ---------------------------------------------------------------------------
__global__ __launch_bounds__(256, 2) void cab_out(const ushort* __restrict__ Fbb,
                                                  const ushort* __restrict__ FtF,
                                                  const float* __restrict__ c2g,
                                                  float* __restrict__ out) {
  const int b = blockIdx.x & 7, mb0 = (blockIdx.x >> 3) * 64;
  const ushort* Fb = Fbb + (size_t)b * NT * DD;
  const ushort* Fr = FtF + (size_t)b * DD * NT;
  const float* c2p = c2g + (size_t)b * NT;

  const int t = threadIdx.x, lane = t & 63, wv = t >> 6;
  const int lcol = lane & 15, hi = lane >> 4;
  const int mh = wv & 1, nh = wv >> 1;

  // 58368 B: FnB 3 x 16384 | Wt 4 x 2304
  __shared__ __align__(16) char LB[58368];
  char* Wt = LB + 49152 + wv * 2304;

  int fnoff[4];
#pragma unroll
  for (int i = 0; i < 4; ++i) {
    int L = i * 256 + t;
    int n = L >> 4, cn = (L & 15) ^ (n & 15);
    fnoff[i] = n * DD + cn * 8;
  }

  // G1 B-operand: wave's 32 m-rows in registers
  bf16x8 fmf[2][4];
#pragma unroll
  for (int ms = 0; ms < 2; ++ms)
#pragma unroll
    for (int ks = 0; ks < 4; ++ks)
      fmf[ms][ks] = *(const bf16x8*)(Fb + (size_t)(mb0 + mh * 32 + ms * 16 + lcol) * DD +
                                     ks * 32 + hi * 8);

  f32x4 accO[8][2];  // [dt][msub]
#pragma unroll
  for (int dt = 0; dt < 8; ++dt)
#pragma unroll
    for (int ms = 0; ms < 2; ++ms) accO[dt][ms] = (f32x4){0.f, 0.f, 0.f, 0.f};

  const ushort* a2w = Fr + (size_t)(nh * 8) * 512 + lane * 8;  // + s*8192 + dt*512
  const float* cw = c2p + nh * 32 + hi * 4;                    // + s*64 (+16 for nt1)

  // prologue: DMA step 0 -> buf0, step 1 -> buf1; retire own DMA(0); barrier.
#pragma unroll
  for (int i = 0; i < 4; ++i) GLOAD16(Fb + fnoff[i], &LB[i * 4096 + wv * 1024]);
#pragma unroll
  for (int i = 0; i < 4; ++i)
    GLOAD16(Fb + 64 * DD + fnoff[i], &LB[16384 + i * 4096 + wv * 1024]);
  __builtin_amdgcn_sched_barrier(0);
  asm volatile("s_waitcnt vmcnt(4)" ::: "memory");
  SBAR();

  int rb = 0, db = 2;  // read buf = s%3, dma buf = (s+2)%3
  for (int s = 0; s < 64; ++s) {
    // group 1: a2 + cv register loads (pinned FIRST so their wait spares DMA(s+2))
    __builtin_amdgcn_sched_barrier(0);
    bf16x8 a2[8];
    const ushort* ap = a2w + (size_t)s * 8192;
#pragma unroll
    for (int dt = 0; dt < 8; ++dt) a2[dt] = *(const bf16x8*)(ap + dt * 512);
    float4 cv0 = *(const float4*)(cw + s * 64);
    float4 cv1 = *(const float4*)(cw + s * 64 + 16);
    __builtin_amdgcn_sched_barrier(0);

    // group 2: DMA(s+2) into buf db
    if (s < 62) {
      const ushort* fs = Fb + (size_t)(s + 2) * 64 * DD;
      char* dst = LB + db * 16384;
#pragma unroll
      for (int i = 0; i < 4; ++i) GLOAD16(fs + fnoff[i], dst + i * 4096 + wv * 1024);
    }
    __builtin_amdgcn_sched_barrier(0);

    // G1: S[wave's 32 n][wave's 32 m] from buf rb; ks-chain == k1 -> same S
    const char* FnB = LB + rb * 16384;
    f32x4 sacc[2][2];  // [nt][msub]
#pragma unroll
    for (int nt = 0; nt < 2; ++nt)
#pragma unroll
      for (int ms = 0; ms < 2; ++ms) sacc[nt][ms] = (f32x4){0.f, 0.f, 0.f, 0.f};
#pragma unroll
    for (int nt = 0; nt < 2; ++nt)
#pragma unroll
      for (int ks = 0; ks < 4; ++ks) {
        int n = (nh * 2 + nt) * 16 + lcol;
        bf16x8 a = *(const bf16x8*)&FnB[n * 256 + (((ks * 4 + hi) ^ lcol) << 4)];
#pragma unroll
        for (int ms = 0; ms < 2; ++ms) sacc[nt][ms] = MFMA16(a, fmf[ms][ks], sacc[nt][ms]);
      }

    // W = 2^(S*L2E + c2) -> wave-private Wt [32 m][72 B rows]
#pragma unroll
    for (int nt = 0; nt < 2; ++nt) {
      float4 cv = nt ? cv1 : cv0;
#pragma unroll
      for (int ms = 0; ms < 2; ++ms) {
        ushort4 wp;
        wp.x = bfc(__builtin_amdgcn_exp2f(fmaf(sacc[nt][ms][0], L2E, cv.x)));
        wp.y = bfc(__builtin_amdgcn_exp2f(fmaf(sacc[nt][ms][1], L2E, cv.y)));
        wp.z = bfc(__builtin_amdgcn_exp2f(fmaf(sacc[nt][ms][2], L2E, cv.z)));
        wp.w = bfc(__builtin_amdgcn_exp2f(fmaf(sacc[nt][ms][3], L2E, cv.w)));
        *(ushort4*)&Wt[(ms * 16 + lcol) * 72 + nt * 32 + hi * 8] = wp;
      }
    }

    // G2: accO[dt][ms] += A2(FtFrag regs) x Wt(B)  (same-wave LDS dep only;
    // compiler's a2 vmcnt wait here retires DMA(s+1) -> barrier publishes it)
    bf16x8 b2[2];
#pragma unroll
    for (int ms = 0; ms < 2; ++ms) {
      const char* p = &Wt[(ms * 16 + lcol) * 72 + hi * 16];
      uint2 lo = *(const uint2*)p;
      uint2 h2 = *(const uint2*)(p + 8);
      b2[ms] = __builtin_bit_cast(bf16x8, (u32x4){lo.x, lo.y, h2.x, h2.y});
    }
#pragma unroll
    for (int dt = 0; dt < 8; ++dt)
#pragma unroll
      for (int ms = 0; ms < 2; ++ms) accO[dt][ms] = MFMA16(a2[dt], b2[ms], accO[dt][ms]);

    SBAR();  // plain s_barrier: no vmcnt(0) drain
    rb = (rb == 2) ? 0 : rb + 1;
    db = (db == 2) ? 0 : db + 1;
  }

  // epilogue: sum nh-partials via LDS overlay
  __syncthreads();
  float* red = (float*)LB;
  if (nh == 1) {
#pragma unroll
    for (int dt = 0; dt < 8; ++dt)
#pragma unroll
      for (int ms = 0; ms < 2; ++ms)
#pragma unroll
        for (int r = 0; r < 4; ++r)
          red[mh * 4096 + (dt * 8 + ms * 4 + r) * 64 + lane] = accO[dt][ms][r];
  }
  __syncthreads();
  if (nh == 0) {
    float* Ob = out + (size_t)b * DD * NT;
#pragma unroll
    for (int dt = 0; dt < 8; ++dt)
#pragma unroll
      for (int ms = 0; ms < 2; ++ms)
#pragma unroll
        for (int r = 0; r < 4; ++r) {
          float v = accO[dt][ms][r] + red[mh * 4096 + (dt * 8 + ms * 4 + r) * 64 + lane];
          Ob[(size_t)(dt * 16 + hi * 4 + r) * NT + mb0 + mh * 32 + ms * 16 + lcol] = v;
        }
  }
}

extern "C" void kernel_launch(void* const* d_in, const int* in_sizes, int n_in,
                              void* d_out, int out_size, void* d_ws, size_t ws_size,
                              hipStream_t stream) {
  const float* x = (const float*)d_in[0];
  float* out = (float*)d_out;
  char* ws = (char*)d_ws;
  ushort* Fbb = (ushort*)ws;                         // 8 MB
  ushort* FtF = (ushort*)(ws + (8u << 20));          // 8 MB (fragment-major F^T)
  float* nrm = (float*)(ws + (16u << 20));           // 128 KB
  float* mxf = (float*)(ws + (16u << 20) + 131072);  // 32 B (pad to 1 KB)
  float* c2 = (float*)(ws + (16u << 20) + 132096);   // 128 KB

  hipMemsetAsync(mxf, 0, 8 * sizeof(float), stream);  // atomicMax target
  hipLaunchKernelGGL(cab_prep, dim3(512), dim3(256), 0, stream, x, Fbb, FtF, nrm,
                     (unsigned int*)mxf);
  hipLaunchKernelGGL(cab_rowstats, dim3(512), dim3(256), 0, stream, Fbb, nrm, mxf, c2);
  hipLaunchKernelGGL(cab_out, dim3(512), dim3(256), 0, stream, Fbb, FtF, c2, out);
}

// Round 15
// 131.979 us; speedup vs baseline: 1.5996x; 1.1109x over previous
//
#include <hip/hip_runtime.h>

// ChannelAttentionBlock: per batch b, F = x[b] viewed as [4096,128] (row-major).
// S = F F^T ; P = softmax rows ; out[b] = F^T P -> [128, 4096].
//
// k0 cab_prep    : Fbb=bf16(x); FtFrag = fragment-major F^T; nrm; bmax.
// k0b cab_mx     : mxf[b] = max over batch-b block maxes
// k1 cab_rowstats: c2[n] = nsh_n - log2 sum_m 2^(S*L2E + nsh_n)  (C-S shift)
// k2 cab_out     : recompute S, W = 2^(S*L2E + c2) (wave-private LDS), O += F^T W
//                  G2 A-frags = coalesced 16B/lane loads from L2-resident FtFrag.
//
// MEASURED-BEST configuration (round 11: total 132.1 us, cab_out 85.5 us).
// Reverted here after v12 (no-staging, 169), v13 (wave-private vmcnt, 105),
// v14 (triple-buffer plain-barrier, 97) all regressed vs this structure.
// S bytes/chain order identical in k1/k2 (bit-exact between passes).

typedef __attribute__((ext_vector_type(8))) __bf16 bf16x8;
typedef __attribute__((ext_vector_type(4))) float f32x4;
typedef __attribute__((ext_vector_type(4))) unsigned int u32x4;

#define MFMA16(a, b, c) __builtin_amdgcn_mfma_f32_16x16x32_bf16((a), (b), (c), 0, 0, 0)
#define GLOAD16(g, l)                                                       \
  __builtin_amdgcn_global_load_lds(                                         \
      (const __attribute__((address_space(1))) void*)(g),                   \
      (__attribute__((address_space(3))) void*)(l), 16, 0, 0)
#define GLOAD4(g, l)                                                        \
  __builtin_amdgcn_global_load_lds(                                         \
      (const __attribute__((address_space(1))) void*)(g),                   \
      (__attribute__((address_space(3))) void*)(l), 4, 0, 0)

static constexpr int NT = 4096;
static constexpr int DD = 128;
static constexpr float L2E = 1.4426950408889634f;

__device__ __forceinline__ unsigned short bfc(float f) {
  return __builtin_bit_cast(unsigned short, (__bf16)f);
}
__device__ __forceinline__ float bf2f(unsigned short u) {
  return (float)__builtin_bit_cast(__bf16, u);
}

// ---------------------------------------------------------------------------
// k0: fused cast + fragment-transpose + row norms. grid 512: b=blk&7, n0-block.
// FtFrag layout (per batch, 1 MB): chunk = (s*2 + nh)*8 + dt  (s = n-step),
//   chunk holds 64 lanes x 16B; lane l covers d = dt*16 + (l&15),
//   n = s*64 + nh*32 + (l>>4)*8 + j, j=0..7.
// ---------------------------------------------------------------------------
__global__ __launch_bounds__(256) void cab_prep(const float* __restrict__ x,
                                                ushort* __restrict__ Fbb,
                                                ushort* __restrict__ FtF,
                                                float* __restrict__ nrm,
                                                float* __restrict__ bmax) {
  const int blk = blockIdx.x;
  const int b = blk & 7, n0 = (blk >> 3) * 64;
  const float* F = x + ((size_t)b * NT + n0) * DD;
  ushort* Fo = Fbb + ((size_t)b * NT + n0) * DD;
  ushort* To = FtF + (size_t)b * DD * NT;

  __shared__ ushort T[128 * 68];  // [d][n-local], stride 136 B (8B-aligned rows)
  __shared__ float redw[4];

  const int t = threadIdx.x, seg = t & 15, rl = t >> 4;
  float lmax = 0.f;

#pragma unroll
  for (int i = 0; i < 4; ++i) {
    const int r = i * 16 + rl;
    float4 u = *(const float4*)(F + (size_t)r * DD + seg * 8);
    float4 v = *(const float4*)(F + (size_t)r * DD + seg * 8 + 4);
    ushort w[8] = {bfc(u.x), bfc(u.y), bfc(u.z), bfc(u.w),
                   bfc(v.x), bfc(v.y), bfc(v.z), bfc(v.w)};
    *(ushort4*)(Fo + (size_t)r * DD + seg * 8) = make_ushort4(w[0], w[1], w[2], w[3]);
    *(ushort4*)(Fo + (size_t)r * DD + seg * 8 + 4) = make_ushort4(w[4], w[5], w[6], w[7]);
    float s = 0.f;
#pragma unroll
    for (int j = 0; j < 8; ++j) {
      T[(seg * 8 + j) * 68 + r] = w[j];
      float f = bf2f(w[j]);
      s = fmaf(f, f, s);
    }
#pragma unroll
    for (int off = 1; off < 16; off <<= 1) s += __shfl_xor(s, off, 64);
    float rn = sqrtf(s);
    if (seg == 0) nrm[(size_t)b * NT + n0 + r] = rn;
    lmax = fmaxf(lmax, rn);
  }
#pragma unroll
  for (int off = 1; off < 64; off <<= 1) lmax = fmaxf(lmax, __shfl_xor(lmax, off, 64));
  if ((t & 63) == 0) redw[t >> 6] = lmax;
  __syncthreads();
  if (t == 0) bmax[blk] = fmaxf(fmaxf(redw[0], redw[1]), fmaxf(redw[2], redw[3]));

  // fragment-transpose out: idx -> (nh = idx>>9, dt = (idx>>6)&7, ln = idx&63)
#pragma unroll
  for (int i = 0; i < 4; ++i) {
    int idx = i * 256 + t;
    int nh = idx >> 9, dt = (idx >> 6) & 7, ln = idx & 63;
    int d = dt * 16 + (ln & 15), nl = nh * 32 + (ln >> 4) * 8;
    const ushort* p = &T[d * 68 + nl];
    uint2 q0 = *(const uint2*)p;
    uint2 q1 = *(const uint2*)(p + 4);
    u32x4 q = {q0.x, q0.y, q1.x, q1.y};
    *(u32x4*)(To + (size_t)(((n0 >> 6) * 2 + nh) * 8 + dt) * 512 + ln * 8) = q;
  }
}

// ---------------------------------------------------------------------------
// k0b: per-batch max of block maxes. grid 8 x 64.
// ---------------------------------------------------------------------------
__global__ __launch_bounds__(64) void cab_mx(const float* __restrict__ bmax,
                                             float* __restrict__ mxf) {
  const int b = blockIdx.x, l = threadIdx.x;
  float m = bmax[l * 8 + b];
#pragma unroll
  for (int off = 1; off < 64; off <<= 1) m = fmaxf(m, __shfl_xor(m, off, 64));
  if (l == 0) mxf[b] = m;
}

// ---------------------------------------------------------------------------
// k1: c2 stats. grid 512: b=blk&7, nb=(blk>>3)*64. Full-m pass, 1 barrier/step.
// ---------------------------------------------------------------------------
__global__ __launch_bounds__(256, 4) void cab_rowstats(const ushort* __restrict__ Fbb,
                                                       const float* __restrict__ nrm,
                                                       const float* __restrict__ mxf,
                                                       float* __restrict__ c2g) {
  const int b = blockIdx.x & 7;
  const int nb = (blockIdx.x >> 3) * 64;
  const ushort* Fb = Fbb + (size_t)b * NT * DD;

  const int t = threadIdx.x, lane = t & 63, wv = t >> 6;
  const int lcol = lane & 15, hi = lane >> 4;
  const int nh = wv >> 1, mq = wv & 1;

  __shared__ __align__(16) char FmB[2][16384];  // [64 m][16 chunks], swz ^(m&15)
  __shared__ float zred[64];

  int fmoff[4];
#pragma unroll
  for (int i = 0; i < 4; ++i) {
    int L = i * 256 + t;
    int m = L >> 4, c = (L & 15) ^ (m & 15);
    fmoff[i] = m * DD + c * 8;
  }

  bf16x8 afr[2][4];
#pragma unroll
  for (int nt = 0; nt < 2; ++nt)
#pragma unroll
    for (int ks = 0; ks < 4; ++ks)
      afr[nt][ks] = *(const bf16x8*)(Fb + (size_t)(nb + nh * 32 + nt * 16 + lcol) * DD +
                                     ks * 32 + hi * 8);

  const float mxv = mxf[b] * L2E;
  float nsh[8];
#pragma unroll
  for (int nt = 0; nt < 2; ++nt)
#pragma unroll
    for (int r = 0; r < 4; ++r)
      nsh[nt * 4 + r] = -nrm[(size_t)b * NT + nb + nh * 32 + nt * 16 + hi * 4 + r] * mxv;

#pragma unroll
  for (int i = 0; i < 4; ++i) GLOAD16(Fb + fmoff[i], &FmB[0][i * 4096 + wv * 1024]);
  __syncthreads();

  float zloc[8];
#pragma unroll
  for (int i = 0; i < 8; ++i) zloc[i] = 0.f;

  for (int s = 0; s < 64; ++s) {
    const int cur = s & 1;
    if (s < 63) {
      const ushort* src = Fb + (size_t)(s + 1) * 64 * DD;
#pragma unroll
      for (int i = 0; i < 4; ++i)
        GLOAD16(src + fmoff[i], &FmB[cur ^ 1][i * 4096 + wv * 1024]);
    }

    f32x4 sacc[2][2];
#pragma unroll
    for (int nt = 0; nt < 2; ++nt)
#pragma unroll
      for (int ms = 0; ms < 2; ++ms) sacc[nt][ms] = (f32x4){0.f, 0.f, 0.f, 0.f};
#pragma unroll
    for (int ms = 0; ms < 2; ++ms)
#pragma unroll
      for (int ks = 0; ks < 4; ++ks) {
        int ml = mq * 32 + ms * 16 + lcol;
        bf16x8 bb = *(const bf16x8*)&FmB[cur][ml * 256 + (((ks * 4 + hi) ^ lcol) << 4)];
#pragma unroll
        for (int nt = 0; nt < 2; ++nt) sacc[nt][ms] = MFMA16(afr[nt][ks], bb, sacc[nt][ms]);
      }
#pragma unroll
    for (int nt = 0; nt < 2; ++nt)
#pragma unroll
      for (int r = 0; r < 4; ++r)
        zloc[nt * 4 + r] += __builtin_amdgcn_exp2f(fmaf(sacc[nt][0][r], L2E, nsh[nt * 4 + r])) +
                            __builtin_amdgcn_exp2f(fmaf(sacc[nt][1][r], L2E, nsh[nt * 4 + r]));
    __syncthreads();
  }

#pragma unroll
  for (int i = 0; i < 8; ++i) {
#pragma unroll
    for (int off = 1; off < 16; off <<= 1) zloc[i] += __shfl_xor(zloc[i], off, 64);
  }
  if (mq == 1 && lcol == 0) {
#pragma unroll
    for (int i = 0; i < 8; ++i) zred[nh * 32 + (i >> 2) * 16 + hi * 4 + (i & 3)] = zloc[i];
  }
  __syncthreads();
  if (mq == 0 && lcol == 0) {
#pragma unroll
    for (int i = 0; i < 8; ++i) {
      int nloc = nh * 32 + (i >> 2) * 16 + hi * 4 + (i & 3);
      c2g[(size_t)b * NT + nb + nloc] = nsh[i] - __log2f(zloc[i] + zred[nloc]);
    }
  }
}

// ---------------------------------------------------------------------------
// k2: O = F^T W. grid 512: b=blk&7, mb0=(blk>>3)*64. 42.5 KB LDS.
// Wave (mh=wv&1, nh=wv>>1): 32 m x 32 n per step; fmf in regs; W wave-private;
// double-buffered FnB, 1 barrier/step; G2 A-frags = coalesced 16B/lane global
// loads from FtFrag (L2-resident, issued at step top).  [measured: 85.5 us]
// ---------------------------------------------------------------------------
__global__ __launch_bounds__(256, 2) void cab_out(const ushort* __restrict__ Fbb,
                                                  const ushort* __restrict__ FtF,
                                                  const float* __restrict__ c2g,
                                                  float* __restrict__ out) {
  const int b = blockIdx.x & 7, mb0 = (blockIdx.x >> 3) * 64;
  const ushort* Fb = Fbb + (size_t)b * NT * DD;
  const ushort* Fr = FtF + (size_t)b * DD * NT;
  const float* c2p = c2g + (size_t)b * NT;

  const int t = threadIdx.x, lane = t & 63, wv = t >> 6;
  const int lcol = lane & 15, hi = lane >> 4;
  const int mh = wv & 1, nh = wv >> 1;

  // 42496 B: FnB 2x16K | Wt 9216 | c2l 512
  __shared__ __align__(16) char LB[42496];
  char* FnB = LB;                     // [64 n][16 chunks], swz ^(n&15), double buf
  char* Wt = LB + 32768;              // 4 x [32 m][72 B] wave-private
  float* c2l = (float*)(LB + 41984);  // [2][64]

  int fnoff[4];
#pragma unroll
  for (int i = 0; i < 4; ++i) {
    int L = i * 256 + t;
    int n = L >> 4, cn = (L & 15) ^ (n & 15);
    fnoff[i] = n * DD + cn * 8;
  }

  // G1 B-operand: wave's 32 m-rows in registers
  bf16x8 fmf[2][4];
#pragma unroll
  for (int ms = 0; ms < 2; ++ms)
#pragma unroll
    for (int ks = 0; ks < 4; ++ks)
      fmf[ms][ks] = *(const bf16x8*)(Fb + (size_t)(mb0 + mh * 32 + ms * 16 + lcol) * DD +
                                     ks * 32 + hi * 8);

  f32x4 accO[8][2];  // [dt][msub]
#pragma unroll
  for (int dt = 0; dt < 8; ++dt)
#pragma unroll
    for (int ms = 0; ms < 2; ++ms) accO[dt][ms] = (f32x4){0.f, 0.f, 0.f, 0.f};

  // prologue: stage step 0
#pragma unroll
  for (int i = 0; i < 4; ++i) GLOAD16(Fb + fnoff[i], &FnB[i * 4096 + wv * 1024]);
  if (wv == 0) GLOAD4(c2p + lane, &c2l[0]);
  __syncthreads();

  const unsigned wtbase = wv * 2304;
  const ushort* a2w = Fr + (size_t)(nh * 8) * 512 + lane * 8;  // + s*8192 + dt*512

  for (int s = 0; s < 64; ++s) {
    const int cur = s & 1;

    // G2-A from FtFrag (perfectly coalesced 16B/lane)
    const ushort* ap = a2w + (size_t)s * 8192;
    bf16x8 a2[8];
#pragma unroll
    for (int dt = 0; dt < 8; ++dt) a2[dt] = *(const bf16x8*)(ap + dt * 512);

    // DMA next step
    if (s < 63) {
      const ushort* fs = Fb + (size_t)(s + 1) * 64 * DD;
#pragma unroll
      for (int i = 0; i < 4; ++i)
        GLOAD16(fs + fnoff[i], &FnB[(cur ^ 1) * 16384 + i * 4096 + wv * 1024]);
      if (wv == 0) GLOAD4(c2p + (s + 1) * 64 + lane, &c2l[((s + 1) & 1) * 64]);
    }

    // G1: S[wave's 32 n][wave's 32 m]; chain identical to k1 -> same S
    f32x4 sacc[2][2];  // [nt][msub]
#pragma unroll
    for (int nt = 0; nt < 2; ++nt)
#pragma unroll
      for (int ms = 0; ms < 2; ++ms) sacc[nt][ms] = (f32x4){0.f, 0.f, 0.f, 0.f};
#pragma unroll
    for (int nt = 0; nt < 2; ++nt)
#pragma unroll
      for (int ks = 0; ks < 4; ++ks) {
        int n = (nh * 2 + nt) * 16 + lcol;
        bf16x8 a = *(const bf16x8*)&FnB[cur * 16384 + n * 256 +
                                        (((ks * 4 + hi) ^ lcol) << 4)];
#pragma unroll
        for (int ms = 0; ms < 2; ++ms) sacc[nt][ms] = MFMA16(a, fmf[ms][ks], sacc[nt][ms]);
      }

    // W = 2^(S*L2E + c2) -> wave-private Wt [32 m][72 B rows]
#pragma unroll
    for (int nt = 0; nt < 2; ++nt) {
      float4 cv = *(const float4*)&c2l[(s & 1) * 64 + nh * 32 + nt * 16 + hi * 4];
#pragma unroll
      for (int ms = 0; ms < 2; ++ms) {
        ushort4 wp;
        wp.x = bfc(__builtin_amdgcn_exp2f(fmaf(sacc[nt][ms][0], L2E, cv.x)));
        wp.y = bfc(__builtin_amdgcn_exp2f(fmaf(sacc[nt][ms][1], L2E, cv.y)));
        wp.z = bfc(__builtin_amdgcn_exp2f(fmaf(sacc[nt][ms][2], L2E, cv.z)));
        wp.w = bfc(__builtin_amdgcn_exp2f(fmaf(sacc[nt][ms][3], L2E, cv.w)));
        *(ushort4*)&Wt[wtbase + (ms * 16 + lcol) * 72 + nt * 32 + hi * 8] = wp;
      }
    }

    // G2: accO[dt][ms] += A2(FtFrag regs) x Wt(B)  (same-wave LDS dep only)
    bf16x8 b2[2];
#pragma unroll
    for (int ms = 0; ms < 2; ++ms) {
      const char* p = &Wt[wtbase + (ms * 16 + lcol) * 72 + hi * 16];
      uint2 lo = *(const uint2*)p;
      uint2 h2 = *(const uint2*)(p + 8);
      b2[ms] = __builtin_bit_cast(bf16x8, (u32x4){lo.x, lo.y, h2.x, h2.y});
    }
#pragma unroll
    for (int dt = 0; dt < 8; ++dt)
#pragma unroll
      for (int ms = 0; ms < 2; ++ms) accO[dt][ms] = MFMA16(a2[dt], b2[ms], accO[dt][ms]);

    __syncthreads();  // drain DMA, flip buffers (only barrier in the step)
  }

  // epilogue: sum nh-partials via LDS (FnB = 32 KB scratch), store f32
  float* red = (float*)LB;
  if (nh == 1) {
#pragma unroll
    for (int dt = 0; dt < 8; ++dt)
#pragma unroll
      for (int ms = 0; ms < 2; ++ms)
#pragma unroll
        for (int r = 0; r < 4; ++r)
          red[mh * 4096 + (dt * 8 + ms * 4 + r) * 64 + lane] = accO[dt][ms][r];
  }
  __syncthreads();
  if (nh == 0) {
    float* Ob = out + (size_t)b * DD * NT;
#pragma unroll
    for (int dt = 0; dt < 8; ++dt)
#pragma unroll
      for (int ms = 0; ms < 2; ++ms)
#pragma unroll
        for (int r = 0; r < 4; ++r) {
          float v = accO[dt][ms][r] + red[mh * 4096 + (dt * 8 + ms * 4 + r) * 64 + lane];
          Ob[(size_t)(dt * 16 + hi * 4 + r) * NT + mb0 + mh * 32 + ms * 16 + lcol] = v;
        }
  }
}

extern "C" void kernel_launch(void* const* d_in, const int* in_sizes, int n_in,
                              void* d_out, int out_size, void* d_ws, size_t ws_size,
                              hipStream_t stream) {
  const float* x = (const float*)d_in[0];
  float* out = (float*)d_out;
  char* ws = (char*)d_ws;
  ushort* Fbb = (ushort*)ws;                         // 8 MB
  ushort* FtF = (ushort*)(ws + (8u << 20));          // 8 MB (fragment-major F^T)
  float* nrm = (float*)(ws + (16u << 20));           // 128 KB
  float* bmax = (float*)(ws + (16u << 20) + 131072); // 2 KB
  float* mxf = (float*)(ws + (16u << 20) + 133120);  // 32 B (pad to 1 KB)
  float* c2 = (float*)(ws + (16u << 20) + 134144);   // 128 KB

  hipLaunchKernelGGL(cab_prep, dim3(512), dim3(256), 0, stream, x, Fbb, FtF, nrm, bmax);
  hipLaunchKernelGGL(cab_mx, dim3(8), dim3(64), 0, stream, bmax, mxf);
  hipLaunchKernelGGL(cab_rowstats, dim3(512), dim3(256), 0, stream, Fbb, nrm, mxf, c2);
  hipLaunchKernelGGL(cab_out, dim3(512), dim3(256), 0, stream, Fbb, FtF, c2, out);
}